// Round 13
// baseline (791.525 us; speedup 1.0000x reference)
//
#include <hip/hip_runtime.h>
#include <hip/hip_bf16.h>
#include <cstdint>

#define DEV __device__ __forceinline__

constexpr int Bt = 16384;   // batch
constexpr int Dd = 1024;    // input dim
constexpr int Hh = 4096;    // hidden
constexpr int Cc = 512;     // classes
constexpr int Ee = 8;       // experts
constexpr int PCAP = 34816; // 32768 pairs + 8*256 padding headroom (multiple of 256)

typedef short bf16x8 __attribute__((ext_vector_type(8)));
typedef ushort u16x8 __attribute__((ext_vector_type(8)));
typedef float f32x4  __attribute__((ext_vector_type(4)));

DEV ushort f2bf(float f){
  uint32_t u = __float_as_uint(f);
  u += 0x7fffu + ((u >> 16) & 1u);
  return (ushort)(u >> 16);
}
DEV float bf2f(ushort u){ return __uint_as_float(((uint32_t)u) << 16); }

// branchless tanh-approx GELU (max |err| vs erf-GELU ~5e-4, << bf16 rounding)
DEV float gelu_t(float x){
  float x2 = x * x;
  float z = x * (0.7978845608f + 0.0356774081f * x2);
  float t = __builtin_amdgcn_exp2f(z * -2.8853900818f);   // exp(-2z)
  return x * __builtin_amdgcn_rcpf(1.f + t);
}

typedef const __attribute__((address_space(1))) void* gptr_t;
typedef __attribute__((address_space(3))) void* lptr_t;
DEV void gload_lds16(const void* g, void* l){
  __builtin_amdgcn_global_load_lds((gptr_t)g, (lptr_t)l, 16, 0, 0);
}

#define BARRIER() __builtin_amdgcn_s_barrier()
// counted lgkm wait + sched fence (rule #18: MFMA must not hoist past the wait)
#define WAITL(N) do { asm volatile("s_waitcnt lgkmcnt(" #N ")" ::: "memory"); \
                      __builtin_amdgcn_sched_barrier(0); } while(0)
#define WAITV(N) asm volatile("s_waitcnt vmcnt(" #N ")" ::: "memory")

// ------- fused router + fp32->bf16 convert: logits, top-2, xb (one x read) -------
__global__ __launch_bounds__(256) void k_routercvt(
    const float* __restrict__ x, const float* __restrict__ gw,
    const float* __restrict__ gb, float* __restrict__ logits,
    int2* __restrict__ topi, float2* __restrict__ topp, ushort* __restrict__ xb)
{
  __shared__ float lgwT[Ee * Dd];
  int tid = threadIdx.x;
  const float4* gw4 = (const float4*)gw;
  for (int i = tid; i < Dd * Ee / 4; i += 256){
    float4 v = gw4[i];
    int d = i >> 1, e0 = (i & 1) * 4;
    lgwT[(e0 + 0) * Dd + d] = v.x;
    lgwT[(e0 + 1) * Dd + d] = v.y;
    lgwT[(e0 + 2) * Dd + d] = v.z;
    lgwT[(e0 + 3) * Dd + d] = v.w;
  }
  __syncthreads();
  int wv = tid >> 6, lane = tid & 63;
  int t = blockIdx.x * 4 + wv;
  const float4* xr4 = (const float4*)(x + (size_t)t * Dd);
  ushort* xbr = xb + (size_t)t * Dd;
  float acc[Ee];
  #pragma unroll
  for (int e = 0; e < Ee; e++) acc[e] = 0.f;
  #pragma unroll
  for (int i = 0; i < 4; i++){
    int d4 = i * 256 + lane * 4;          // element index (multiple of 4)
    float4 xs = xr4[d4 >> 2];
    ushort4 o; o.x = f2bf(xs.x); o.y = f2bf(xs.y); o.z = f2bf(xs.z); o.w = f2bf(xs.w);
    *(ushort4*)(xbr + d4) = o;
    #pragma unroll
    for (int e = 0; e < Ee; e++){
      float4 wv4 = *(const float4*)(lgwT + e * Dd + d4);
      acc[e] += xs.x * wv4.x + xs.y * wv4.y + xs.z * wv4.z + xs.w * wv4.w;
    }
  }
  #pragma unroll
  for (int e = 0; e < Ee; e++){
    #pragma unroll
    for (int m = 1; m < 64; m <<= 1) acc[e] += __shfl_xor(acc[e], m, 64);
  }
  if (lane == 0){
    float lg[Ee];
    #pragma unroll
    for (int e = 0; e < Ee; e++) lg[e] = acc[e] + gb[e];
    #pragma unroll
    for (int e = 0; e < Ee; e++) logits[(size_t)t * Ee + e] = lg[e];
    int i0 = 0; float v0 = lg[0];
    #pragma unroll
    for (int e = 1; e < Ee; e++) if (lg[e] > v0){ v0 = lg[e]; i0 = e; }
    int i1 = (i0 == 0) ? 1 : 0; float v1 = lg[i1];
    #pragma unroll
    for (int e = 0; e < Ee; e++) if (e != i0 && lg[e] > v1){ v1 = lg[e]; i1 = e; }
    float ex = expf(v1 - v0);
    float p0 = 1.f / (1.f + ex);
    float p1 = ex * p0;
    topi[t] = make_int2(i0, i1);
    topp[t] = make_float2(p0, p1);
  }
}

// ---------------- histogram + padded segment offsets (256-aligned) ----------------
__global__ __launch_bounds__(256) void k_offsets(
    const int2* __restrict__ topi, int* __restrict__ off)
{
  __shared__ int part[4][8];
  int tid = threadIdx.x, lane = tid & 63, w = tid >> 6;
  int c0 = 0, c1 = 0, c2 = 0, c3 = 0, c4 = 0, c5 = 0, c6 = 0, c7 = 0;
  for (int t = tid; t < Bt; t += 256){
    int2 ii = topi[t];
    c0 += (ii.x == 0) + (ii.y == 0);
    c1 += (ii.x == 1) + (ii.y == 1);
    c2 += (ii.x == 2) + (ii.y == 2);
    c3 += (ii.x == 3) + (ii.y == 3);
    c4 += (ii.x == 4) + (ii.y == 4);
    c5 += (ii.x == 5) + (ii.y == 5);
    c6 += (ii.x == 6) + (ii.y == 6);
    c7 += (ii.x == 7) + (ii.y == 7);
  }
  #pragma unroll
  for (int m = 1; m < 64; m <<= 1){
    c0 += __shfl_xor(c0, m, 64); c1 += __shfl_xor(c1, m, 64);
    c2 += __shfl_xor(c2, m, 64); c3 += __shfl_xor(c3, m, 64);
    c4 += __shfl_xor(c4, m, 64); c5 += __shfl_xor(c5, m, 64);
    c6 += __shfl_xor(c6, m, 64); c7 += __shfl_xor(c7, m, 64);
  }
  if (lane == 0){
    part[w][0] = c0; part[w][1] = c1; part[w][2] = c2; part[w][3] = c3;
    part[w][4] = c4; part[w][5] = c5; part[w][6] = c6; part[w][7] = c7;
  }
  __syncthreads();
  if (tid == 0){
    int a = 0;
    for (int e = 0; e < Ee; e++){
      int h = part[0][e] + part[1][e] + part[2][e] + part[3][e];
      off[e] = a; a += ((h + 255) >> 8) << 8;
    }
    off[Ee] = a;
  }
}

// ---------------- scatter pairs into expert segments (hierarchical) ----------------
__global__ __launch_bounds__(256) void k_scatter(
    const int2* __restrict__ topi, const int* __restrict__ off,
    int* __restrict__ fill, int* __restrict__ ptok, int2* __restrict__ pidx)
{
  __shared__ int lcnt[8], lbase[8];
  int tid = threadIdx.x;
  if (tid < 8) lcnt[tid] = 0;
  __syncthreads();
  int t = blockIdx.x * 256 + tid;
  int2 ii = topi[t];
  int r0 = atomicAdd(&lcnt[ii.x], 1);
  int r1 = atomicAdd(&lcnt[ii.y], 1);
  __syncthreads();
  if (tid < 8) lbase[tid] = off[tid] + atomicAdd(&fill[tid], lcnt[tid]);
  __syncthreads();
  int p0 = lbase[ii.x] + r0;
  int p1 = lbase[ii.y] + r1;
  ptok[p0] = t;
  ptok[p1] = t;
  pidx[t] = make_int2(p0, p1);
}

// ---------------- per-expert transpose fp32 [R][Cd] -> bf16 [Cd][R] ----------------
__global__ __launch_bounds__(256) void k_transpose_bf16(
    const float* __restrict__ in, ushort* __restrict__ outp, int R, int Cd)
{
  __shared__ float tl[64][65];
  size_t eoff = (size_t)blockIdx.z * (size_t)R * (size_t)Cd;
  int c0 = blockIdx.x * 64, r0 = blockIdx.y * 64;
  int tid = threadIdx.x;
  int r = tid >> 2, cq = tid & 3;
  const float* src = in + eoff + (size_t)(r0 + r) * Cd + c0 + cq * 16;
  #pragma unroll
  for (int q = 0; q < 4; q++){
    float4 v = ((const float4*)src)[q];
    int cc = cq * 16 + q * 4;
    tl[r][cc + 0] = v.x; tl[r][cc + 1] = v.y; tl[r][cc + 2] = v.z; tl[r][cc + 3] = v.w;
  }
  __syncthreads();
  int c = tid >> 2, rq = tid & 3;
  ushort* dst = outp + eoff + (size_t)(c0 + c) * R + r0 + rq * 16;
  #pragma unroll
  for (int q = 0; q < 4; q++){
    ushort4 o;
    o.x = f2bf(tl[rq * 16 + q * 4 + 0][c]);
    o.y = f2bf(tl[rq * 16 + q * 4 + 1][c]);
    o.z = f2bf(tl[rq * 16 + q * 4 + 2][c]);
    o.w = f2bf(tl[rq * 16 + q * 4 + 3][c]);
    ((ushort4*)dst)[q] = o;
  }
}

// --------- 128x128 double-buffered grouped GEMM — 64KB LDS = 2 blocks/CU -----
// MODE 0: h = gather(x) @ w1t[e]^T + b1 -> bf16 h (chunk-local rows)
// MODE 1: y[ks-plane][pair] = h[ks-range] @ w2t[e]^T (+b2 in ks=0)
// Mechanism bet: 2 independent blocks per CU (m114) — when one block's waves
// stall at lgkm/barrier, the other block's wave on each SIMD issues MFMAs.
// Buffer: [A 128x64 | B 128x64] x 2, rows of 8 slots x 16B, slot ^= (row&7).
// Schedule per K-tile (round-6 counted-lgkm, best measured):
//   reads(16) ; WAITL(4) ; 16 MFMA ; WAITL(0) ; 16 MFMA ; BAR ;
//   stage(t+2) ; WAITV(8) ; BAR.

DEV void read_A8(bf16x8 (&aq)[4][2], const char* buf, int wm, const uint32_t (&alane)[2]){
  #pragma unroll
  for (int mi = 0; mi < 4; mi++)
    #pragma unroll
    for (int k2 = 0; k2 < 2; k2++)
      aq[mi][k2] = *(const bf16x8*)(buf + wm * 8192 + mi * 2048 + alane[k2]);
}
template<int P>   // P=0: bq[0..1] (ni 0,1); P=1: bq[2..3]
DEV void read_B4(bf16x8 (&bq)[4][2], const char* buf, int wn, const uint32_t (&alane)[2]){
  #pragma unroll
  for (int j = 0; j < 2; j++)
    #pragma unroll
    for (int k2 = 0; k2 < 2; k2++)
      bq[P * 2 + j][k2] = *(const bf16x8*)(buf + 16384 + wn * 8192 +
                                           (P * 2 + j) * 2048 + alane[k2]);
}
template<int P>
DEV void mfma16(f32x4 (&acc)[4][4], const bf16x8 (&aq)[4][2], const bf16x8 (&bq)[4][2]){
  #pragma unroll
  for (int mi = 0; mi < 4; mi++)
    #pragma unroll
    for (int j = 0; j < 2; j++)
      #pragma unroll
      for (int k2 = 0; k2 < 2; k2++)
        acc[mi][P * 2 + j] = __builtin_amdgcn_mfma_f32_16x16x32_bf16(
            aq[mi][k2], bq[P * 2 + j][k2], acc[mi][P * 2 + j], 0, 0, 0);
}
DEV void stage8(const char* Ab, const char* Bb, const uint32_t (&a_src)[4],
                const uint32_t (&b_src)[4], uint32_t ko, char* buf, int tid){
  #pragma unroll
  for (int g = 0; g < 4; g++)
    gload_lds16(Ab + a_src[g] + ko, buf + g * 4096 + tid * 16);
  #pragma unroll
  for (int g = 0; g < 4; g++)
    gload_lds16(Bb + b_src[g] + ko, buf + 16384 + g * 4096 + tid * 16);
}

template<int MODE, int Kd, int Nd, int KS>
__global__ __launch_bounds__(256, 2) void k_gemm(
    const ushort* __restrict__ A, const ushort* __restrict__ Bm,
    const float* __restrict__ bias, const int* __restrict__ off,
    const int* __restrict__ ptok, ushort* __restrict__ Outp, int chunk_base,
    int plane_elems)
{
  __shared__ char lds[65536];
  constexpr int Kh  = Kd / KS;   // K-range per split plane
  constexpr int NTk = Kh / 64;   // K tiles
  constexpr int NTn = Nd / 128;  // N tiles
  // bijective XCD swizzle (m204); (n,ks)-fastest, m outer
  int nwg = gridDim.x;
  int orig = blockIdx.x;
  int q = nwg >> 3, r8 = nwg & 7;
  int xcd = orig & 7, lin = orig >> 3;
  int swz = (xcd < r8 ? xcd * (q + 1) : r8 * (q + 1) + (xcd - r8) * q) + lin;
  int inner = swz % (NTn * KS);
  int m = swz / (NTn * KS);
  int nI = inner % NTn, ksI = inner / NTn;
  int r0l = m * 128;
  int n0 = nI * 128;
  uint32_t kbyte = (uint32_t)ksI * (uint32_t)(Kh * 2);
  int grow0 = chunk_base + r0l;
  if (grow0 >= off[8]) return;   // block-uniform early out (off[8] 256-aligned)

  int tid = threadIdx.x;
  int e = 0;
  #pragma unroll
  for (int i = 1; i < 8; i++) e = (grow0 >= off[i]) ? i : e;

  // ---- staging source addresses (inverse-swizzled global, linear LDS dest) ----
  uint32_t sx = (uint32_t)(((tid & 7) ^ ((tid >> 3) & 7)) << 4);
  int rh = tid >> 3;                 // 0..31, gload g covers rows g*32 + rh
  uint32_t a_src[4], b_src[4];
  #pragma unroll
  for (int g = 0; g < 4; g++){
    int ra = g * 32 + rh;
    uint32_t rowb;
    if (MODE == 0) rowb = (uint32_t)ptok[grow0 + ra] * (uint32_t)(Kd * 2);
    else           rowb = (uint32_t)(r0l + ra) * (uint32_t)(Kd * 2);
    a_src[g] = rowb + kbyte + sx;
    b_src[g] = (uint32_t)(e * Nd + n0 + ra) * (uint32_t)(Kd * 2) + kbyte + sx;
  }
  const char* Ab = (const char*)A;
  const char* Bb = (const char*)Bm;
  int w = tid >> 6, lane = tid & 63;
  int wm = w >> 1, wn = w & 1;          // 2M x 2N waves, wave owns 64x64
  int l15 = lane & 15, lhi = lane >> 4;

  uint32_t alane[2];
  #pragma unroll
  for (int k2 = 0; k2 < 2; k2++)
    alane[k2] = (uint32_t)(l15 * 128 + (((k2 * 4 + lhi) ^ (l15 & 7)) << 4));

  f32x4 acc[4][4];
  #pragma unroll
  for (int mi = 0; mi < 4; mi++)
    #pragma unroll
    for (int ni = 0; ni < 4; ni++) acc[mi][ni] = (f32x4){0.f, 0.f, 0.f, 0.f};
  bf16x8 aq[4][2], bq[4][2];

  // ---- prologue: stage tiles 0 and 1 ----
  stage8(Ab, Bb, a_src, b_src, 0u,   lds,         tid);
  stage8(Ab, Bb, a_src, b_src, 128u, lds + 32768, tid);
  WAITV(8);            // tile0's 8 retired; tile1's 8 in flight
  BARRIER();

  // ---- main loop: 2 barriers per K-tile ----
  #pragma unroll 1
  for (int t = 0; t < NTk; ++t){
    const char* buf = lds + (t & 1) * 32768;
    char* sbuf = lds + (t & 1) * 32768;
    // 16 ds_reads: RA(8), RB01(4), RB23(4) — in order
    read_A8(aq, buf, wm, alane);
    read_B4<0>(bq, buf, wn, alane);
    read_B4<1>(bq, buf, wn, alane);
    WAITL(4);                            // RA+RB01 done, RB23 in flight
    __builtin_amdgcn_s_setprio(1);
    mfma16<0>(acc, aq, bq);
    __builtin_amdgcn_s_setprio(0);
    WAITL(0);                            // RB23 done
    __builtin_amdgcn_s_setprio(1);
    mfma16<1>(acc, aq, bq);
    __builtin_amdgcn_s_setprio(0);
    BARRIER();                           // all waves done reading buf[t]
    if (t + 2 < NTk){
      stage8(Ab, Bb, a_src, b_src, (uint32_t)(t + 2) * 128u, sbuf, tid);
      WAITV(8);                          // t+1's loads retired; t+2's in flight
    } else if (t + 1 < NTk){
      WAITV(0);                          // drain last staging
    }
    BARRIER();                           // buf[(t+1)&1] staged for all waves
  }

  // ---- epilogue: C/D map col = lane&15, row = (lane>>4)*4 + reg ----
  float bv[4]; int nn[4];
  #pragma unroll
  for (int ni = 0; ni < 4; ni++){
    nn[ni] = n0 + wn * 64 + ni * 16 + l15;
    bv[ni] = (MODE == 0 || ksI == 0) ? bias[e * Nd + nn[ni]] : 0.f;
  }
  ushort* OutP = Outp + (size_t)ksI * (size_t)plane_elems;
  #pragma unroll
  for (int mi = 0; mi < 4; mi++){
    #pragma unroll
    for (int r = 0; r < 4; r++){
      int rl = r0l + wm * 64 + mi * 16 + lhi * 4 + r;
      size_t rowbase = (MODE == 0) ? (size_t)rl * Nd
                                   : (size_t)(chunk_base + rl) * Nd;
      #pragma unroll
      for (int ni = 0; ni < 4; ni++){
        float v = acc[mi][ni][r] + bv[ni];
        OutP[rowbase + nn[ni]] = f2bf(v);
      }
    }
  }
}

// ---------------- LayerNorm + tanh-GELU, one block per row, coalesced ----------------
__global__ __launch_bounds__(256) void k_lngelu(
    ushort* __restrict__ h, const int* __restrict__ off,
    const float* __restrict__ lng, const float* __restrict__ lnb, int chunk_base)
{
  __shared__ float redS[8];
  int rl = blockIdx.x, tid = threadIdx.x;
  int grow = chunk_base + rl;
  if (grow >= off[8]) return;
  int e = 0;
  #pragma unroll
  for (int i = 1; i < 8; i++) e = (grow >= off[i]) ? i : e;
  ushort* hr = h + (size_t)rl * Hh;
  // chunk c = i*256+tid, elements [4c, 4c+4): all wave accesses contiguous
  float xv[16];
  #pragma unroll
  for (int i = 0; i < 4; i++){
    int c = i * 256 + tid;
    ushort4 v = *(const ushort4*)(hr + c * 4);
    xv[i * 4 + 0] = bf2f(v.x); xv[i * 4 + 1] = bf2f(v.y);
    xv[i * 4 + 2] = bf2f(v.z); xv[i * 4 + 3] = bf2f(v.w);
  }
  float s0 = 0.f, s1 = 0.f;
  #pragma unroll
  for (int i = 0; i < 16; i++){ s0 += xv[i]; s1 += xv[i] * xv[i]; }
  #pragma unroll
  for (int m = 1; m < 64; m <<= 1){ s0 += __shfl_xor(s0, m, 64); s1 += __shfl_xor(s1, m, 64); }
  int w = tid >> 6;
  if ((tid & 63) == 0){ redS[w * 2] = s0; redS[w * 2 + 1] = s1; }
  __syncthreads();
  s0 = redS[0] + redS[2] + redS[4] + redS[6];
  s1 = redS[1] + redS[3] + redS[5] + redS[7];
  float mu = s0 * (1.f / 4096.f);
  float var = s1 * (1.f / 4096.f) - mu * mu;
  float rs = rsqrtf(var + 1e-5f);
  const float4* gp = (const float4*)(lng + (size_t)e * Hh);
  const float4* bp = (const float4*)(lnb + (size_t)e * Hh);
  #pragma unroll
  for (int i = 0; i < 4; i++){
    int c = i * 256 + tid;
    float4 g = gp[c], b = bp[c];
    float v0 = (xv[i * 4 + 0] - mu) * rs * g.x + b.x;
    float v1 = (xv[i * 4 + 1] - mu) * rs * g.y + b.y;
    float v2 = (xv[i * 4 + 2] - mu) * rs * g.z + b.z;
    float v3 = (xv[i * 4 + 3] - mu) * rs * g.w + b.w;
    ushort4 o;
    o.x = f2bf(gelu_t(v0)); o.y = f2bf(gelu_t(v1));
    o.z = f2bf(gelu_t(v2)); o.w = f2bf(gelu_t(v3));
    *(ushort4*)(hr + c * 4) = o;
  }
}

// -------- combine: out[t] = p0*(y0[p0]+y1[p0]) + p1*(y0[p1]+y1[p1]) --------
__global__ __launch_bounds__(128) void k_combine(
    const ushort* __restrict__ y, int plane, const int2* __restrict__ pidx,
    const float2* __restrict__ topp, float* __restrict__ outp)
{
  int t = blockIdx.x;
  int c4 = threadIdx.x << 2;
  int2 pi = pidx[t]; float2 pp = topp[t];
  ushort4 a0 = *(const ushort4*)(y + (size_t)pi.x * Cc + c4);
  ushort4 a1 = *(const ushort4*)(y + (size_t)plane + (size_t)pi.x * Cc + c4);
  ushort4 b0 = *(const ushort4*)(y + (size_t)pi.y * Cc + c4);
  ushort4 b1 = *(const ushort4*)(y + (size_t)plane + (size_t)pi.y * Cc + c4);
  float4 o;
  o.x = pp.x * (bf2f(a0.x) + bf2f(a1.x)) + pp.y * (bf2f(b0.x) + bf2f(b1.x));
  o.y = pp.x * (bf2f(a0.y) + bf2f(a1.y)) + pp.y * (bf2f(b0.y) + bf2f(b1.y));
  o.z = pp.x * (bf2f(a0.z) + bf2f(a1.z)) + pp.y * (bf2f(b0.z) + bf2f(b1.z));
  o.w = pp.x * (bf2f(a0.w) + bf2f(a1.w)) + pp.y * (bf2f(b0.w) + bf2f(b1.w));
  *(float4*)(outp + (size_t)t * Cc + c4) = o;
}

// ---------------- host launch ----------------
extern "C" void kernel_launch(void* const* d_in, const int* in_sizes, int n_in,
                              void* d_out, int out_size, void* d_ws, size_t ws_size,
                              hipStream_t stream)
{
  const float* x   = (const float*)d_in[0];
  const float* gw  = (const float*)d_in[1];
  const float* gb  = (const float*)d_in[2];
  const float* w1  = (const float*)d_in[3];
  const float* b1  = (const float*)d_in[4];
  const float* lng = (const float*)d_in[5];
  const float* lnb = (const float*)d_in[6];
  const float* w2  = (const float*)d_in[7];
  const float* b2  = (const float*)d_in[8];
  float* outp   = (float*)d_out;
  float* logits = outp + (size_t)Bt * Cc;

  constexpr int YPLANE = PCAP * Cc;   // elements per split-K plane

  char* p = (char*)d_ws;
  auto alloc = [&](size_t bytes) -> char* {
    char* q = p; p += (bytes + 255) & ~(size_t)255; return q;
  };
  int*    ctrl  = (int*)alloc(256);            // fill[8] @ +8 | off[9] @ +16
  int* fill = ctrl + 8; int* off = ctrl + 16;
  int2*   topi  = (int2*)alloc((size_t)Bt * 8);
  float2* topp  = (float2*)alloc((size_t)Bt * 8);
  int2*   pidx  = (int2*)alloc((size_t)Bt * 8);
  int*    ptok  = (int*)alloc((size_t)PCAP * 4);
  ushort* ybuf  = (ushort*)alloc((size_t)YPLANE * 2 * 2);   // 2 planes bf16
  ushort* xb    = (ushort*)alloc((size_t)Bt * Dd * 2);
  ushort* w1t   = (ushort*)alloc((size_t)Ee * Hh * Dd * 2);
  ushort* w2t   = (ushort*)alloc((size_t)Ee * Cc * Hh * 2);
  size_t used  = (size_t)(p - (char*)d_ws);
  size_t avail = ws_size > used ? ws_size - used : 0;
  long long chr = (long long)(avail / ((size_t)Hh * 2));
  chr &= ~255LL;
  int CH = (int)(chr < 256 ? 256 : (chr > PCAP ? (long long)PCAP : chr));
  ushort* hbuf = (ushort*)p;   // CH x Hh bf16

  hipMemsetAsync(ctrl, 0, 256, stream);
  hipMemsetAsync(ptok, 0, (size_t)PCAP * 4, stream);

  k_routercvt<<<Bt / 4, 256, 0, stream>>>(x, gw, gb, logits, topi, topp, xb);
  k_offsets<<<1, 256, 0, stream>>>(topi, off);
  k_scatter<<<Bt / 256, 256, 0, stream>>>(topi, off, fill, ptok, pidx);
  k_transpose_bf16<<<dim3(Hh / 64, Dd / 64, Ee), 256, 0, stream>>>(w1, w1t, Dd, Hh);
  k_transpose_bf16<<<dim3(Cc / 64, Hh / 64, Ee), 256, 0, stream>>>(w2, w2t, Hh, Cc);

  for (int base = 0; base < PCAP; base += CH){
    int rows = (PCAP - base < CH) ? (PCAP - base) : CH;
    int nb1 = (rows / 128) * (Hh / 128);
    k_gemm<0, Dd, Hh, 1><<<nb1, 256, 0, stream>>>(xb, w1t, b1, off, ptok, hbuf, base, 0);
    k_lngelu<<<rows, 256, 0, stream>>>(hbuf, off, lng, lnb, base);
    int nb2 = (rows / 128) * (Cc / 128) * 2;
    k_gemm<1, Hh, Cc, 2><<<nb2, 256, 0, stream>>>(hbuf, w2t, b2, off, ptok, ybuf, base, YPLANE);
  }
  k_combine<<<Bt, 128, 0, stream>>>(ybuf, YPLANE, pidx, topp, outp);
}

// Round 14
// 768.014 us; speedup vs baseline: 1.0306x; 1.0306x over previous
//
#include <hip/hip_runtime.h>
#include <hip/hip_bf16.h>
#include <cstdint>

#define DEV __device__ __forceinline__

constexpr int Bt = 16384;   // batch
constexpr int Dd = 1024;    // input dim
constexpr int Hh = 4096;    // hidden
constexpr int Cc = 512;     // classes
constexpr int Ee = 8;       // experts
constexpr int PCAP = 34816; // 32768 pairs + 8*256 padding headroom (multiple of 256)
constexpr int CHMAX = 17408; // h-chunk rows: 17408*4096*2B = 142MB -> L3-resident

typedef short bf16x8 __attribute__((ext_vector_type(8)));
typedef ushort u16x8 __attribute__((ext_vector_type(8)));
typedef float f32x4  __attribute__((ext_vector_type(4)));

DEV ushort f2bf(float f){
  uint32_t u = __float_as_uint(f);
  u += 0x7fffu + ((u >> 16) & 1u);
  return (ushort)(u >> 16);
}
DEV float bf2f(ushort u){ return __uint_as_float(((uint32_t)u) << 16); }

// branchless tanh-approx GELU (max |err| vs erf-GELU ~5e-4, << bf16 rounding)
DEV float gelu_t(float x){
  float x2 = x * x;
  float z = x * (0.7978845608f + 0.0356774081f * x2);
  float t = __builtin_amdgcn_exp2f(z * -2.8853900818f);   // exp(-2z)
  return x * __builtin_amdgcn_rcpf(1.f + t);
}

typedef const __attribute__((address_space(1))) void* gptr_t;
typedef __attribute__((address_space(3))) void* lptr_t;
DEV void gload_lds16(const void* g, void* l){
  __builtin_amdgcn_global_load_lds((gptr_t)g, (lptr_t)l, 16, 0, 0);
}

#define BARRIER() __builtin_amdgcn_s_barrier()
// counted lgkm wait + sched fence (rule #18: MFMA must not hoist past the wait)
#define WAITL(N) do { asm volatile("s_waitcnt lgkmcnt(" #N ")" ::: "memory"); \
                      __builtin_amdgcn_sched_barrier(0); } while(0)
#define WAITV(N) asm volatile("s_waitcnt vmcnt(" #N ")" ::: "memory")

// ------- fused router + fp32->bf16 convert: logits, top-2, xb (one x read) -------
__global__ __launch_bounds__(256) void k_routercvt(
    const float* __restrict__ x, const float* __restrict__ gw,
    const float* __restrict__ gb, float* __restrict__ logits,
    int2* __restrict__ topi, float2* __restrict__ topp, ushort* __restrict__ xb)
{
  __shared__ float lgwT[Ee * Dd];
  int tid = threadIdx.x;
  const float4* gw4 = (const float4*)gw;
  for (int i = tid; i < Dd * Ee / 4; i += 256){
    float4 v = gw4[i];
    int d = i >> 1, e0 = (i & 1) * 4;
    lgwT[(e0 + 0) * Dd + d] = v.x;
    lgwT[(e0 + 1) * Dd + d] = v.y;
    lgwT[(e0 + 2) * Dd + d] = v.z;
    lgwT[(e0 + 3) * Dd + d] = v.w;
  }
  __syncthreads();
  int wv = tid >> 6, lane = tid & 63;
  int t = blockIdx.x * 4 + wv;
  const float4* xr4 = (const float4*)(x + (size_t)t * Dd);
  ushort* xbr = xb + (size_t)t * Dd;
  float acc[Ee];
  #pragma unroll
  for (int e = 0; e < Ee; e++) acc[e] = 0.f;
  #pragma unroll
  for (int i = 0; i < 4; i++){
    int d4 = i * 256 + lane * 4;          // element index (multiple of 4)
    float4 xs = xr4[d4 >> 2];
    ushort4 o; o.x = f2bf(xs.x); o.y = f2bf(xs.y); o.z = f2bf(xs.z); o.w = f2bf(xs.w);
    *(ushort4*)(xbr + d4) = o;
    #pragma unroll
    for (int e = 0; e < Ee; e++){
      float4 wv4 = *(const float4*)(lgwT + e * Dd + d4);
      acc[e] += xs.x * wv4.x + xs.y * wv4.y + xs.z * wv4.z + xs.w * wv4.w;
    }
  }
  #pragma unroll
  for (int e = 0; e < Ee; e++){
    #pragma unroll
    for (int m = 1; m < 64; m <<= 1) acc[e] += __shfl_xor(acc[e], m, 64);
  }
  if (lane == 0){
    float lg[Ee];
    #pragma unroll
    for (int e = 0; e < Ee; e++) lg[e] = acc[e] + gb[e];
    #pragma unroll
    for (int e = 0; e < Ee; e++) logits[(size_t)t * Ee + e] = lg[e];
    int i0 = 0; float v0 = lg[0];
    #pragma unroll
    for (int e = 1; e < Ee; e++) if (lg[e] > v0){ v0 = lg[e]; i0 = e; }
    int i1 = (i0 == 0) ? 1 : 0; float v1 = lg[i1];
    #pragma unroll
    for (int e = 0; e < Ee; e++) if (e != i0 && lg[e] > v1){ v1 = lg[e]; i1 = e; }
    float ex = expf(v1 - v0);
    float p0 = 1.f / (1.f + ex);
    float p1 = ex * p0;
    topi[t] = make_int2(i0, i1);
    topp[t] = make_float2(p0, p1);
  }
}

// ---------------- histogram + padded segment offsets (256-aligned) ----------------
__global__ __launch_bounds__(256) void k_offsets(
    const int2* __restrict__ topi, int* __restrict__ off)
{
  __shared__ int part[4][8];
  int tid = threadIdx.x, lane = tid & 63, w = tid >> 6;
  int c0 = 0, c1 = 0, c2 = 0, c3 = 0, c4 = 0, c5 = 0, c6 = 0, c7 = 0;
  for (int t = tid; t < Bt; t += 256){
    int2 ii = topi[t];
    c0 += (ii.x == 0) + (ii.y == 0);
    c1 += (ii.x == 1) + (ii.y == 1);
    c2 += (ii.x == 2) + (ii.y == 2);
    c3 += (ii.x == 3) + (ii.y == 3);
    c4 += (ii.x == 4) + (ii.y == 4);
    c5 += (ii.x == 5) + (ii.y == 5);
    c6 += (ii.x == 6) + (ii.y == 6);
    c7 += (ii.x == 7) + (ii.y == 7);
  }
  #pragma unroll
  for (int m = 1; m < 64; m <<= 1){
    c0 += __shfl_xor(c0, m, 64); c1 += __shfl_xor(c1, m, 64);
    c2 += __shfl_xor(c2, m, 64); c3 += __shfl_xor(c3, m, 64);
    c4 += __shfl_xor(c4, m, 64); c5 += __shfl_xor(c5, m, 64);
    c6 += __shfl_xor(c6, m, 64); c7 += __shfl_xor(c7, m, 64);
  }
  if (lane == 0){
    part[w][0] = c0; part[w][1] = c1; part[w][2] = c2; part[w][3] = c3;
    part[w][4] = c4; part[w][5] = c5; part[w][6] = c6; part[w][7] = c7;
  }
  __syncthreads();
  if (tid == 0){
    int a = 0;
    for (int e = 0; e < Ee; e++){
      int h = part[0][e] + part[1][e] + part[2][e] + part[3][e];
      off[e] = a; a += ((h + 255) >> 8) << 8;
    }
    off[Ee] = a;
  }
}

// ---------------- scatter pairs into expert segments (hierarchical) ----------------
__global__ __launch_bounds__(256) void k_scatter(
    const int2* __restrict__ topi, const int* __restrict__ off,
    int* __restrict__ fill, int* __restrict__ ptok, int2* __restrict__ pidx)
{
  __shared__ int lcnt[8], lbase[8];
  int tid = threadIdx.x;
  if (tid < 8) lcnt[tid] = 0;
  __syncthreads();
  int t = blockIdx.x * 256 + tid;
  int2 ii = topi[t];
  int r0 = atomicAdd(&lcnt[ii.x], 1);
  int r1 = atomicAdd(&lcnt[ii.y], 1);
  __syncthreads();
  if (tid < 8) lbase[tid] = off[tid] + atomicAdd(&fill[tid], lcnt[tid]);
  __syncthreads();
  int p0 = lbase[ii.x] + r0;
  int p1 = lbase[ii.y] + r1;
  ptok[p0] = t;
  ptok[p1] = t;
  pidx[t] = make_int2(p0, p1);
}

// ---------------- per-expert transpose fp32 [R][Cd] -> bf16 [Cd][R] ----------------
__global__ __launch_bounds__(256) void k_transpose_bf16(
    const float* __restrict__ in, ushort* __restrict__ outp, int R, int Cd)
{
  __shared__ float tl[64][65];
  size_t eoff = (size_t)blockIdx.z * (size_t)R * (size_t)Cd;
  int c0 = blockIdx.x * 64, r0 = blockIdx.y * 64;
  int tid = threadIdx.x;
  int r = tid >> 2, cq = tid & 3;
  const float* src = in + eoff + (size_t)(r0 + r) * Cd + c0 + cq * 16;
  #pragma unroll
  for (int q = 0; q < 4; q++){
    float4 v = ((const float4*)src)[q];
    int cc = cq * 16 + q * 4;
    tl[r][cc + 0] = v.x; tl[r][cc + 1] = v.y; tl[r][cc + 2] = v.z; tl[r][cc + 3] = v.w;
  }
  __syncthreads();
  int c = tid >> 2, rq = tid & 3;
  ushort* dst = outp + eoff + (size_t)(c0 + c) * R + r0 + rq * 16;
  #pragma unroll
  for (int q = 0; q < 4; q++){
    ushort4 o;
    o.x = f2bf(tl[rq * 16 + q * 4 + 0][c]);
    o.y = f2bf(tl[rq * 16 + q * 4 + 1][c]);
    o.z = f2bf(tl[rq * 16 + q * 4 + 2][c]);
    o.w = f2bf(tl[rq * 16 + q * 4 + 3][c]);
    ((ushort4*)dst)[q] = o;
  }
}

// --------- 4-phase-per-K-tile 256x256 grouped GEMM (m201 template port) ------
// MODE 0: h = gather(x) @ w1t[e]^T + b1 -> bf16 h (chunk-local rows)
// MODE 1: y[ks-plane][pair] = h[ks-range] @ w2t[e]^T (+b2 in ks=0)
// LDS: 2 buffers x { A: 2 halves x [128][64] bf16, B: same } = 131072 B.
// Half-tile layout: [128 rows][8 slots x 16B], slot stored = slot ^ (row&7).
// Per phase: {ds-reads | stage ONE half-tile (2 gloads) | bar | lgkm0 |
//             setprio(1) 16 MFMA setprio(0) | bar}; A(t+1) staged P0/P1 into
// the other buffer, B(t+2) staged P2/P3 into this buffer (regions free after
// P1's trailing barrier); WAITV(4) once per tile at P3 — never vmcnt(0).

DEV void read_Aq(bf16x8 (&aq)[4][2], const char* lb, int abase, const uint32_t (&alane)[2]){
  #pragma unroll
  for (int i = 0; i < 4; i++)
    #pragma unroll
    for (int k2 = 0; k2 < 2; k2++)
      aq[i][k2] = *(const bf16x8*)(lb + abase + i * 2048 + alane[k2]);
}
template<int P>   // P=0: bq[0..1] (ni 0,1); P=1: bq[2..3]
DEV void read_Bp(bf16x8 (&bq)[4][2], const char* lb, int wn, const uint32_t (&alane)[2]){
  #pragma unroll
  for (int j = 0; j < 2; j++)
    #pragma unroll
    for (int k2 = 0; k2 < 2; k2++)
      bq[P * 2 + j][k2] = *(const bf16x8*)(lb + 32768 + (wn >> 1) * 16384 +
                              (wn & 1) * 8192 + P * 4096 + j * 2048 + alane[k2]);
}
template<int MQ, int NB>
DEV void mfma_half(f32x4 (&acc)[8][4], const bf16x8 (&a)[4][2], const bf16x8 (&b)[4][2]){
  #pragma unroll
  for (int i = 0; i < 4; i++)
    #pragma unroll
    for (int j = 0; j < 2; j++)
      #pragma unroll
      for (int k2 = 0; k2 < 2; k2++)
        acc[MQ * 4 + i][NB * 2 + j] = __builtin_amdgcn_mfma_f32_16x16x32_bf16(
            a[i][k2], b[NB * 2 + j][k2], acc[MQ * 4 + i][NB * 2 + j], 0, 0, 0);
}
DEV void stage_half(const char* gb, const uint32_t* src2, uint32_t ko, char* dstbase){
  gload_lds16(gb + src2[0] + ko, dstbase);
  gload_lds16(gb + src2[1] + ko, dstbase + 8192);
}

template<int MODE, int Kd, int Nd, int KS>
__global__ __launch_bounds__(512, 2) void k_gemm8(
    const ushort* __restrict__ A, const ushort* __restrict__ Bm,
    const float* __restrict__ bias, const int* __restrict__ off,
    const int* __restrict__ ptok, ushort* __restrict__ Outp, int chunk_base,
    int plane_elems)
{
  __shared__ char lds[131072];
  constexpr int Kh  = Kd / KS;   // K-range per split plane
  constexpr int NTk = Kh / 64;   // K tiles
  constexpr int NTn = Nd / 256;  // N tiles
  // bijective XCD swizzle (m204); (n,ks)-fastest, m outer
  int nwg = gridDim.x;
  int orig = blockIdx.x;
  int q = nwg >> 3, r8 = nwg & 7;
  int xcd = orig & 7, lin = orig >> 3;
  int swz = (xcd < r8 ? xcd * (q + 1) : r8 * (q + 1) + (xcd - r8) * q) + lin;
  int inner = swz % (NTn * KS);
  int m = swz / (NTn * KS);
  int nI = inner % NTn, ksI = inner / NTn;
  int r0l = m * 256;
  int n0 = nI * 256;
  uint32_t kbyte = (uint32_t)ksI * (uint32_t)(Kh * 2);
  int grow0 = chunk_base + r0l;
  if (grow0 >= off[8]) return;   // block-uniform early out (off[8] 256-aligned)

  int tid = threadIdx.x;
  int e = 0;
  #pragma unroll
  for (int i = 1; i < 8; i++) e = (grow0 >= off[i]) ? i : e;

  // ---- staging source addresses (inverse-swizzled global, linear LDS dest) ----
  uint32_t sx = (uint32_t)(((tid & 7) ^ ((tid >> 3) & 7)) << 4);
  int rh0 = tid >> 3, rh1 = rh0 + 64;
  uint32_t a_src[2][2], b_src[2][2];
  #pragma unroll
  for (int h = 0; h < 2; h++){
    int ra0 = h * 128 + rh0, ra1 = h * 128 + rh1;
    uint32_t rowb0, rowb1;
    if (MODE == 0){
      rowb0 = (uint32_t)ptok[grow0 + ra0] * (uint32_t)(Kd * 2);
      rowb1 = (uint32_t)ptok[grow0 + ra1] * (uint32_t)(Kd * 2);
    } else {
      rowb0 = (uint32_t)(r0l + ra0) * (uint32_t)(Kd * 2);
      rowb1 = (uint32_t)(r0l + ra1) * (uint32_t)(Kd * 2);
    }
    a_src[h][0] = rowb0 + kbyte + sx;
    a_src[h][1] = rowb1 + kbyte + sx;
    b_src[h][0] = (uint32_t)(e * Nd + n0 + ra0) * (uint32_t)(Kd * 2) + kbyte + sx;
    b_src[h][1] = (uint32_t)(e * Nd + n0 + ra1) * (uint32_t)(Kd * 2) + kbyte + sx;
  }
  const char* Ab = (const char*)A;
  const char* Bb = (const char*)Bm;
  int w = tid >> 6, lane = tid & 63;
  int wm = w >> 2, wn = w & 3;          // 2M x 4N waves, wave owns 128x64
  int l15 = lane & 15, lhi = lane >> 4;
  int wso = w * 1024;                   // per-wave stage offset within region
  int abase0 = wm * 16384;              // A quad 0 (rows wm*128 + 0..63)
  int abase1 = wm * 16384 + 8192;       // A quad 1 (rows wm*128 + 64..127)

  uint32_t alane[2];
  #pragma unroll
  for (int k2 = 0; k2 < 2; k2++)
    alane[k2] = (uint32_t)(l15 * 128 + (((k2 * 4 + lhi) ^ (l15 & 7)) << 4));

  f32x4 acc[8][4];
  #pragma unroll
  for (int mi = 0; mi < 8; mi++)
    #pragma unroll
    for (int ni = 0; ni < 4; ni++) acc[mi][ni] = (f32x4){0.f, 0.f, 0.f, 0.f};
  bf16x8 aq[4][2], bq[4][2];

  // ---- prologue: tile0 fully + tile1's B halves (6 half-tiles) ----
  stage_half(Ab, a_src[0], 0u, lds + 0     + wso);
  stage_half(Ab, a_src[1], 0u, lds + 16384 + wso);
  stage_half(Bb, b_src[0], 0u, lds + 32768 + wso);
  stage_half(Bb, b_src[1], 0u, lds + 49152 + wso);
  if (NTk > 1){
    stage_half(Bb, b_src[0], 128u, lds + 65536 + 32768 + wso);
    stage_half(Bb, b_src[1], 128u, lds + 65536 + 49152 + wso);
    WAITV(4);          // tile0's 8 done; tile1's B stays in flight
  } else {
    WAITV(0);
  }
  BARRIER();

  // ---- main loop: 4 phases per K-tile ----
  #pragma unroll 1
  for (int t = 0; t < NTk; ++t){
    const char* lb = lds + (t & 1) * 65536;          // compute buffer
    char* nb = lds + ((t + 1) & 1) * 65536;          // other buffer (A(t+1))
    char* cb = lds + (t & 1) * 65536;                // this buffer (B(t+2))
    uint32_t ko1 = (uint32_t)(t + 1) * 128u;
    uint32_t ko2 = (uint32_t)(t + 2) * 128u;
    // P0: reads (m0 A-quad + B nh0), stage A-h0(t+1)
    read_Aq(aq, lb, abase0, alane);
    read_Bp<0>(bq, lb, wn, alane);
    if (t + 1 < NTk) stage_half(Ab, a_src[0], ko1, nb + wso);
    BARRIER(); WAITL(0);
    __builtin_amdgcn_s_setprio(1);
    mfma_half<0, 0>(acc, aq, bq);
    __builtin_amdgcn_s_setprio(0);
    BARRIER();
    // P1: reads B nh1, stage A-h1(t+1)
    read_Bp<1>(bq, lb, wn, alane);
    if (t + 1 < NTk) stage_half(Ab, a_src[1], ko1, nb + 16384 + wso);
    BARRIER(); WAITL(0);
    __builtin_amdgcn_s_setprio(1);
    mfma_half<0, 1>(acc, aq, bq);
    __builtin_amdgcn_s_setprio(0);
    BARRIER();
    // P2: reads m1 A-quad, stage B-h0(t+2) (B regions of cb free after P1 bar)
    read_Aq(aq, lb, abase1, alane);
    if (t + 2 < NTk) stage_half(Bb, b_src[0], ko2, cb + 32768 + wso);
    BARRIER(); WAITL(0);
    __builtin_amdgcn_s_setprio(1);
    mfma_half<1, 1>(acc, aq, bq);
    __builtin_amdgcn_s_setprio(0);
    BARRIER();
    // P3: no reads; stage B-h1(t+2); counted vmcnt (drains exactly tile t+1)
    if (t + 2 < NTk) stage_half(Bb, b_src[1], ko2, cb + 49152 + wso);
    __builtin_amdgcn_s_setprio(1);
    mfma_half<1, 0>(acc, aq, bq);
    __builtin_amdgcn_s_setprio(0);
    if (t + 2 < NTk)      { WAITV(4); }
    else if (t + 1 < NTk) { WAITV(0); }
    BARRIER();
  }

  // ---- epilogue: C/D map col = lane&15, row = (lane>>4)*4 + reg ----
  float bv[4]; int nn[4];
  #pragma unroll
  for (int ni = 0; ni < 4; ni++){
    nn[ni] = n0 + wn * 64 + ni * 16 + l15;
    bv[ni] = (MODE == 0 || ksI == 0) ? bias[e * Nd + nn[ni]] : 0.f;
  }
  ushort* OutP = Outp + (size_t)ksI * (size_t)plane_elems;
  #pragma unroll
  for (int mi = 0; mi < 8; mi++){
    #pragma unroll
    for (int r = 0; r < 4; r++){
      int rl = r0l + wm * 128 + mi * 16 + lhi * 4 + r;
      size_t rowbase = (MODE == 0) ? (size_t)rl * Nd
                                   : (size_t)(chunk_base + rl) * Nd;
      #pragma unroll
      for (int ni = 0; ni < 4; ni++){
        float v = acc[mi][ni][r] + bv[ni];
        OutP[rowbase + nn[ni]] = f2bf(v);
      }
    }
  }
}

// ---------------- LayerNorm + tanh-GELU, one block per row, coalesced ----------------
__global__ __launch_bounds__(256) void k_lngelu(
    ushort* __restrict__ h, const int* __restrict__ off,
    const float* __restrict__ lng, const float* __restrict__ lnb, int chunk_base)
{
  __shared__ float redS[8];
  int rl = blockIdx.x, tid = threadIdx.x;
  int grow = chunk_base + rl;
  if (grow >= off[8]) return;
  int e = 0;
  #pragma unroll
  for (int i = 1; i < 8; i++) e = (grow >= off[i]) ? i : e;
  ushort* hr = h + (size_t)rl * Hh;
  // chunk c = i*256+tid, elements [4c, 4c+4): all wave accesses contiguous
  float xv[16];
  #pragma unroll
  for (int i = 0; i < 4; i++){
    int c = i * 256 + tid;
    ushort4 v = *(const ushort4*)(hr + c * 4);
    xv[i * 4 + 0] = bf2f(v.x); xv[i * 4 + 1] = bf2f(v.y);
    xv[i * 4 + 2] = bf2f(v.z); xv[i * 4 + 3] = bf2f(v.w);
  }
  float s0 = 0.f, s1 = 0.f;
  #pragma unroll
  for (int i = 0; i < 16; i++){ s0 += xv[i]; s1 += xv[i] * xv[i]; }
  #pragma unroll
  for (int m = 1; m < 64; m <<= 1){ s0 += __shfl_xor(s0, m, 64); s1 += __shfl_xor(s1, m, 64); }
  int w = tid >> 6;
  if ((tid & 63) == 0){ redS[w * 2] = s0; redS[w * 2 + 1] = s1; }
  __syncthreads();
  s0 = redS[0] + redS[2] + redS[4] + redS[6];
  s1 = redS[1] + redS[3] + redS[5] + redS[7];
  float mu = s0 * (1.f / 4096.f);
  float var = s1 * (1.f / 4096.f) - mu * mu;
  float rs = rsqrtf(var + 1e-5f);
  const float4* gp = (const float4*)(lng + (size_t)e * Hh);
  const float4* bp = (const float4*)(lnb + (size_t)e * Hh);
  #pragma unroll
  for (int i = 0; i < 4; i++){
    int c = i * 256 + tid;
    float4 g = gp[c], b = bp[c];
    float v0 = (xv[i * 4 + 0] - mu) * rs * g.x + b.x;
    float v1 = (xv[i * 4 + 1] - mu) * rs * g.y + b.y;
    float v2 = (xv[i * 4 + 2] - mu) * rs * g.z + b.z;
    float v3 = (xv[i * 4 + 3] - mu) * rs * g.w + b.w;
    ushort4 o;
    o.x = f2bf(gelu_t(v0)); o.y = f2bf(gelu_t(v1));
    o.z = f2bf(gelu_t(v2)); o.w = f2bf(gelu_t(v3));
    *(ushort4*)(hr + c * 4) = o;
  }
}

// -------- combine: out[t] = p0*(y0[p0]+y1[p0]) + p1*(y0[p1]+y1[p1]) --------
__global__ __launch_bounds__(128) void k_combine(
    const ushort* __restrict__ y, int plane, const int2* __restrict__ pidx,
    const float2* __restrict__ topp, float* __restrict__ outp)
{
  int t = blockIdx.x;
  int c4 = threadIdx.x << 2;
  int2 pi = pidx[t]; float2 pp = topp[t];
  ushort4 a0 = *(const ushort4*)(y + (size_t)pi.x * Cc + c4);
  ushort4 a1 = *(const ushort4*)(y + (size_t)plane + (size_t)pi.x * Cc + c4);
  ushort4 b0 = *(const ushort4*)(y + (size_t)pi.y * Cc + c4);
  ushort4 b1 = *(const ushort4*)(y + (size_t)plane + (size_t)pi.y * Cc + c4);
  float4 o;
  o.x = pp.x * (bf2f(a0.x) + bf2f(a1.x)) + pp.y * (bf2f(b0.x) + bf2f(b1.x));
  o.y = pp.x * (bf2f(a0.y) + bf2f(a1.y)) + pp.y * (bf2f(b0.y) + bf2f(b1.y));
  o.z = pp.x * (bf2f(a0.z) + bf2f(a1.z)) + pp.y * (bf2f(b0.z) + bf2f(b1.z));
  o.w = pp.x * (bf2f(a0.w) + bf2f(a1.w)) + pp.y * (bf2f(b0.w) + bf2f(b1.w));
  *(float4*)(outp + (size_t)t * Cc + c4) = o;
}

// ---------------- host launch ----------------
extern "C" void kernel_launch(void* const* d_in, const int* in_sizes, int n_in,
                              void* d_out, int out_size, void* d_ws, size_t ws_size,
                              hipStream_t stream)
{
  const float* x   = (const float*)d_in[0];
  const float* gw  = (const float*)d_in[1];
  const float* gb  = (const float*)d_in[2];
  const float* w1  = (const float*)d_in[3];
  const float* b1  = (const float*)d_in[4];
  const float* lng = (const float*)d_in[5];
  const float* lnb = (const float*)d_in[6];
  const float* w2  = (const float*)d_in[7];
  const float* b2  = (const float*)d_in[8];
  float* outp   = (float*)d_out;
  float* logits = outp + (size_t)Bt * Cc;

  constexpr int YPLANE = PCAP * Cc;   // elements per split-K plane

  char* p = (char*)d_ws;
  auto alloc = [&](size_t bytes) -> char* {
    char* q = p; p += (bytes + 255) & ~(size_t)255; return q;
  };
  int*    ctrl  = (int*)alloc(256);            // fill[8] @ +8 | off[9] @ +16
  int* fill = ctrl + 8; int* off = ctrl + 16;
  int2*   topi  = (int2*)alloc((size_t)Bt * 8);
  float2* topp  = (float2*)alloc((size_t)Bt * 8);
  int2*   pidx  = (int2*)alloc((size_t)Bt * 8);
  int*    ptok  = (int*)alloc((size_t)PCAP * 4);
  ushort* ybuf  = (ushort*)alloc((size_t)YPLANE * 2 * 2);   // 2 planes bf16
  ushort* xb    = (ushort*)alloc((size_t)Bt * Dd * 2);
  ushort* w1t   = (ushort*)alloc((size_t)Ee * Hh * Dd * 2);
  ushort* w2t   = (ushort*)alloc((size_t)Ee * Cc * Hh * 2);
  size_t used  = (size_t)(p - (char*)d_ws);
  size_t avail = ws_size > used ? ws_size - used : 0;
  long long chr = (long long)(avail / ((size_t)Hh * 2));
  chr &= ~255LL;
  if (chr > CHMAX) chr = CHMAX;        // cap: keep h-chunk L3-resident (142MB)
  int CH = (int)(chr < 256 ? 256 : (chr > PCAP ? (long long)PCAP : chr));
  ushort* hbuf = (ushort*)p;   // CH x Hh bf16

  hipMemsetAsync(ctrl, 0, 256, stream);
  hipMemsetAsync(ptok, 0, (size_t)PCAP * 4, stream);

  k_routercvt<<<Bt / 4, 256, 0, stream>>>(x, gw, gb, logits, topi, topp, xb);
  k_offsets<<<1, 256, 0, stream>>>(topi, off);
  k_scatter<<<Bt / 256, 256, 0, stream>>>(topi, off, fill, ptok, pidx);
  k_transpose_bf16<<<dim3(Hh / 64, Dd / 64, Ee), 256, 0, stream>>>(w1, w1t, Dd, Hh);
  k_transpose_bf16<<<dim3(Cc / 64, Hh / 64, Ee), 256, 0, stream>>>(w2, w2t, Hh, Cc);

  for (int base = 0; base < PCAP; base += CH){
    int rows = (PCAP - base < CH) ? (PCAP - base) : CH;
    int nb1 = (rows / 256) * (Hh / 256);
    k_gemm8<0, Dd, Hh, 1><<<nb1, 512, 0, stream>>>(xb, w1t, b1, off, ptok, hbuf, base, 0);
    k_lngelu<<<rows, 256, 0, stream>>>(hbuf, off, lng, lnb, base);
    int nb2 = (rows / 256) * (Cc / 256) * 2;
    k_gemm8<1, Hh, Cc, 2><<<nb2, 512, 0, stream>>>(hbuf, w2t, b2, off, ptok, ybuf, base, YPLANE);
  }
  k_combine<<<Bt, 128, 0, stream>>>(ybuf, YPLANE, pidx, topp, outp);
}

// Round 15
// 725.989 us; speedup vs baseline: 1.0903x; 1.0579x over previous
//
#include <hip/hip_runtime.h>
#include <hip/hip_bf16.h>
#include <cstdint>

#define DEV __device__ __forceinline__

constexpr int Bt = 16384;   // batch
constexpr int Dd = 1024;    // input dim
constexpr int Hh = 4096;    // hidden
constexpr int Cc = 512;     // classes
constexpr int Ee = 8;       // experts
constexpr int PCAP = 34816; // 32768 pairs + 8*256 padding headroom (multiple of 256)

typedef short bf16x8 __attribute__((ext_vector_type(8)));
typedef ushort u16x8 __attribute__((ext_vector_type(8)));
typedef float f32x4  __attribute__((ext_vector_type(4)));

DEV ushort f2bf(float f){
  uint32_t u = __float_as_uint(f);
  u += 0x7fffu + ((u >> 16) & 1u);
  return (ushort)(u >> 16);
}
DEV float bf2f(ushort u){ return __uint_as_float(((uint32_t)u) << 16); }

// branchless tanh-approx GELU (max |err| vs erf-GELU ~5e-4, << bf16 rounding)
DEV float gelu_t(float x){
  float x2 = x * x;
  float z = x * (0.7978845608f + 0.0356774081f * x2);
  float t = __builtin_amdgcn_exp2f(z * -2.8853900818f);   // exp(-2z)
  return x * __builtin_amdgcn_rcpf(1.f + t);
}

typedef const __attribute__((address_space(1))) void* gptr_t;
typedef __attribute__((address_space(3))) void* lptr_t;
DEV void gload_lds16(const void* g, void* l){
  __builtin_amdgcn_global_load_lds((gptr_t)g, (lptr_t)l, 16, 0, 0);
}

#define BARRIER() __builtin_amdgcn_s_barrier()
// counted lgkm wait + sched fence (rule #18: MFMA must not hoist past the wait)
#define WAITL(N) do { asm volatile("s_waitcnt lgkmcnt(" #N ")" ::: "memory"); \
                      __builtin_amdgcn_sched_barrier(0); } while(0)
#define WAITV(N) asm volatile("s_waitcnt vmcnt(" #N ")" ::: "memory")

// ------- fused router + fp32->bf16 convert: logits, top-2, xb (one x read) -------
__global__ __launch_bounds__(256) void k_routercvt(
    const float* __restrict__ x, const float* __restrict__ gw,
    const float* __restrict__ gb, float* __restrict__ logits,
    int2* __restrict__ topi, float2* __restrict__ topp, ushort* __restrict__ xb)
{
  __shared__ float lgwT[Ee * Dd];
  int tid = threadIdx.x;
  const float4* gw4 = (const float4*)gw;
  for (int i = tid; i < Dd * Ee / 4; i += 256){
    float4 v = gw4[i];
    int d = i >> 1, e0 = (i & 1) * 4;
    lgwT[(e0 + 0) * Dd + d] = v.x;
    lgwT[(e0 + 1) * Dd + d] = v.y;
    lgwT[(e0 + 2) * Dd + d] = v.z;
    lgwT[(e0 + 3) * Dd + d] = v.w;
  }
  __syncthreads();
  int wv = tid >> 6, lane = tid & 63;
  int t = blockIdx.x * 4 + wv;
  const float4* xr4 = (const float4*)(x + (size_t)t * Dd);
  ushort* xbr = xb + (size_t)t * Dd;
  float acc[Ee];
  #pragma unroll
  for (int e = 0; e < Ee; e++) acc[e] = 0.f;
  #pragma unroll
  for (int i = 0; i < 4; i++){
    int d4 = i * 256 + lane * 4;          // element index (multiple of 4)
    float4 xs = xr4[d4 >> 2];
    ushort4 o; o.x = f2bf(xs.x); o.y = f2bf(xs.y); o.z = f2bf(xs.z); o.w = f2bf(xs.w);
    *(ushort4*)(xbr + d4) = o;
    #pragma unroll
    for (int e = 0; e < Ee; e++){
      float4 wv4 = *(const float4*)(lgwT + e * Dd + d4);
      acc[e] += xs.x * wv4.x + xs.y * wv4.y + xs.z * wv4.z + xs.w * wv4.w;
    }
  }
  #pragma unroll
  for (int e = 0; e < Ee; e++){
    #pragma unroll
    for (int m = 1; m < 64; m <<= 1) acc[e] += __shfl_xor(acc[e], m, 64);
  }
  if (lane == 0){
    float lg[Ee];
    #pragma unroll
    for (int e = 0; e < Ee; e++) lg[e] = acc[e] + gb[e];
    #pragma unroll
    for (int e = 0; e < Ee; e++) logits[(size_t)t * Ee + e] = lg[e];
    int i0 = 0; float v0 = lg[0];
    #pragma unroll
    for (int e = 1; e < Ee; e++) if (lg[e] > v0){ v0 = lg[e]; i0 = e; }
    int i1 = (i0 == 0) ? 1 : 0; float v1 = lg[i1];
    #pragma unroll
    for (int e = 0; e < Ee; e++) if (e != i0 && lg[e] > v1){ v1 = lg[e]; i1 = e; }
    float ex = expf(v1 - v0);
    float p0 = 1.f / (1.f + ex);
    float p1 = ex * p0;
    topi[t] = make_int2(i0, i1);
    topp[t] = make_float2(p0, p1);
  }
}

// ---------------- histogram + padded segment offsets (256-aligned) ----------------
__global__ __launch_bounds__(256) void k_offsets(
    const int2* __restrict__ topi, int* __restrict__ off)
{
  __shared__ int part[4][8];
  int tid = threadIdx.x, lane = tid & 63, w = tid >> 6;
  int c0 = 0, c1 = 0, c2 = 0, c3 = 0, c4 = 0, c5 = 0, c6 = 0, c7 = 0;
  for (int t = tid; t < Bt; t += 256){
    int2 ii = topi[t];
    c0 += (ii.x == 0) + (ii.y == 0);
    c1 += (ii.x == 1) + (ii.y == 1);
    c2 += (ii.x == 2) + (ii.y == 2);
    c3 += (ii.x == 3) + (ii.y == 3);
    c4 += (ii.x == 4) + (ii.y == 4);
    c5 += (ii.x == 5) + (ii.y == 5);
    c6 += (ii.x == 6) + (ii.y == 6);
    c7 += (ii.x == 7) + (ii.y == 7);
  }
  #pragma unroll
  for (int m = 1; m < 64; m <<= 1){
    c0 += __shfl_xor(c0, m, 64); c1 += __shfl_xor(c1, m, 64);
    c2 += __shfl_xor(c2, m, 64); c3 += __shfl_xor(c3, m, 64);
    c4 += __shfl_xor(c4, m, 64); c5 += __shfl_xor(c5, m, 64);
    c6 += __shfl_xor(c6, m, 64); c7 += __shfl_xor(c7, m, 64);
  }
  if (lane == 0){
    part[w][0] = c0; part[w][1] = c1; part[w][2] = c2; part[w][3] = c3;
    part[w][4] = c4; part[w][5] = c5; part[w][6] = c6; part[w][7] = c7;
  }
  __syncthreads();
  if (tid == 0){
    int a = 0;
    for (int e = 0; e < Ee; e++){
      int h = part[0][e] + part[1][e] + part[2][e] + part[3][e];
      off[e] = a; a += ((h + 255) >> 8) << 8;
    }
    off[Ee] = a;
  }
}

// ---------------- scatter pairs into expert segments (hierarchical) ----------------
__global__ __launch_bounds__(256) void k_scatter(
    const int2* __restrict__ topi, const int* __restrict__ off,
    int* __restrict__ fill, int* __restrict__ ptok, int2* __restrict__ pidx)
{
  __shared__ int lcnt[8], lbase[8];
  int tid = threadIdx.x;
  if (tid < 8) lcnt[tid] = 0;
  __syncthreads();
  int t = blockIdx.x * 256 + tid;
  int2 ii = topi[t];
  int r0 = atomicAdd(&lcnt[ii.x], 1);
  int r1 = atomicAdd(&lcnt[ii.y], 1);
  __syncthreads();
  if (tid < 8) lbase[tid] = off[tid] + atomicAdd(&fill[tid], lcnt[tid]);
  __syncthreads();
  int p0 = lbase[ii.x] + r0;
  int p1 = lbase[ii.y] + r1;
  ptok[p0] = t;
  ptok[p1] = t;
  pidx[t] = make_int2(p0, p1);
}

// ---------------- per-expert transpose fp32 [R][Cd] -> bf16 [Cd][R] ----------------
__global__ __launch_bounds__(256) void k_transpose_bf16(
    const float* __restrict__ in, ushort* __restrict__ outp, int R, int Cd)
{
  __shared__ float tl[64][65];
  size_t eoff = (size_t)blockIdx.z * (size_t)R * (size_t)Cd;
  int c0 = blockIdx.x * 64, r0 = blockIdx.y * 64;
  int tid = threadIdx.x;
  int r = tid >> 2, cq = tid & 3;
  const float* src = in + eoff + (size_t)(r0 + r) * Cd + c0 + cq * 16;
  #pragma unroll
  for (int q = 0; q < 4; q++){
    float4 v = ((const float4*)src)[q];
    int cc = cq * 16 + q * 4;
    tl[r][cc + 0] = v.x; tl[r][cc + 1] = v.y; tl[r][cc + 2] = v.z; tl[r][cc + 3] = v.w;
  }
  __syncthreads();
  int c = tid >> 2, rq = tid & 3;
  ushort* dst = outp + eoff + (size_t)(c0 + c) * R + r0 + rq * 16;
  #pragma unroll
  for (int q = 0; q < 4; q++){
    ushort4 o;
    o.x = f2bf(tl[rq * 16 + q * 4 + 0][c]);
    o.y = f2bf(tl[rq * 16 + q * 4 + 1][c]);
    o.z = f2bf(tl[rq * 16 + q * 4 + 2][c]);
    o.w = f2bf(tl[rq * 16 + q * 4 + 3][c]);
    ((ushort4*)dst)[q] = o;
  }
}

// --------- 4-phase-per-K-tile 256x256 grouped GEMM (m201 template port) ------
// MODE 0: h = gather(x) @ w1t[e]^T + b1 -> bf16 h (chunk-local rows)
// MODE 1: y[ks-plane][pair] = h[ks-range] @ w2t[e]^T (+b2 in ks=0)
// LDS: 2 buffers x { A: 2 halves x [128][64] bf16, B: same } = 131072 B.
// Half-tile layout: [128 rows][8 slots x 16B], slot stored = slot ^ (row&7).

DEV void read_Aq(bf16x8 (&aq)[4][2], const char* lb, int abase, const uint32_t (&alane)[2]){
  #pragma unroll
  for (int i = 0; i < 4; i++)
    #pragma unroll
    for (int k2 = 0; k2 < 2; k2++)
      aq[i][k2] = *(const bf16x8*)(lb + abase + i * 2048 + alane[k2]);
}
template<int P>   // P=0: bq[0..1] (ni 0,1); P=1: bq[2..3]
DEV void read_Bp(bf16x8 (&bq)[4][2], const char* lb, int wn, const uint32_t (&alane)[2]){
  #pragma unroll
  for (int j = 0; j < 2; j++)
    #pragma unroll
    for (int k2 = 0; k2 < 2; k2++)
      bq[P * 2 + j][k2] = *(const bf16x8*)(lb + 32768 + (wn >> 1) * 16384 +
                              (wn & 1) * 8192 + P * 4096 + j * 2048 + alane[k2]);
}
template<int MQ, int NB>
DEV void mfma_half(f32x4 (&acc)[8][4], const bf16x8 (&a)[4][2], const bf16x8 (&b)[4][2]){
  #pragma unroll
  for (int i = 0; i < 4; i++)
    #pragma unroll
    for (int j = 0; j < 2; j++)
      #pragma unroll
      for (int k2 = 0; k2 < 2; k2++)
        acc[MQ * 4 + i][NB * 2 + j] = __builtin_amdgcn_mfma_f32_16x16x32_bf16(
            a[i][k2], b[NB * 2 + j][k2], acc[MQ * 4 + i][NB * 2 + j], 0, 0, 0);
}
DEV void stage_half(const char* gb, const uint32_t* src2, uint32_t ko, char* dstbase){
  gload_lds16(gb + src2[0] + ko, dstbase);
  gload_lds16(gb + src2[1] + ko, dstbase + 8192);
}

template<int MODE, int Kd, int Nd, int KS>
__global__ __launch_bounds__(512, 2) void k_gemm8(
    const ushort* __restrict__ A, const ushort* __restrict__ Bm,
    const float* __restrict__ bias, const int* __restrict__ off,
    const int* __restrict__ ptok, ushort* __restrict__ Outp, int chunk_base,
    int plane_elems)
{
  __shared__ char lds[131072];
  constexpr int Kh  = Kd / KS;   // K-range per split plane
  constexpr int NTk = Kh / 64;   // K tiles
  constexpr int NTn = Nd / 256;  // N tiles
  // bijective XCD swizzle (m204); (n,ks)-fastest, m outer
  int nwg = gridDim.x;
  int orig = blockIdx.x;
  int q = nwg >> 3, r8 = nwg & 7;
  int xcd = orig & 7, lin = orig >> 3;
  int swz = (xcd < r8 ? xcd * (q + 1) : r8 * (q + 1) + (xcd - r8) * q) + lin;
  int inner = swz % (NTn * KS);
  int m = swz / (NTn * KS);
  int nI = inner % NTn, ksI = inner / NTn;
  int r0l = m * 256;
  int n0 = nI * 256;
  uint32_t kbyte = (uint32_t)ksI * (uint32_t)(Kh * 2);
  int grow0 = chunk_base + r0l;
  if (grow0 >= off[8]) return;   // block-uniform early out (off[8] 256-aligned)

  int tid = threadIdx.x;
  int e = 0;
  #pragma unroll
  for (int i = 1; i < 8; i++) e = (grow0 >= off[i]) ? i : e;

  // ---- staging source addresses (inverse-swizzled global, linear LDS dest) ----
  uint32_t sx = (uint32_t)(((tid & 7) ^ ((tid >> 3) & 7)) << 4);
  int rh0 = tid >> 3, rh1 = rh0 + 64;
  uint32_t a_src[2][2], b_src[2][2];
  #pragma unroll
  for (int h = 0; h < 2; h++){
    int ra0 = h * 128 + rh0, ra1 = h * 128 + rh1;
    uint32_t rowb0, rowb1;
    if (MODE == 0){
      rowb0 = (uint32_t)ptok[grow0 + ra0] * (uint32_t)(Kd * 2);
      rowb1 = (uint32_t)ptok[grow0 + ra1] * (uint32_t)(Kd * 2);
    } else {
      rowb0 = (uint32_t)(r0l + ra0) * (uint32_t)(Kd * 2);
      rowb1 = (uint32_t)(r0l + ra1) * (uint32_t)(Kd * 2);
    }
    a_src[h][0] = rowb0 + kbyte + sx;
    a_src[h][1] = rowb1 + kbyte + sx;
    b_src[h][0] = (uint32_t)(e * Nd + n0 + ra0) * (uint32_t)(Kd * 2) + kbyte + sx;
    b_src[h][1] = (uint32_t)(e * Nd + n0 + ra1) * (uint32_t)(Kd * 2) + kbyte + sx;
  }
  const char* Ab = (const char*)A;
  const char* Bb = (const char*)Bm;
  int w = tid >> 6, lane = tid & 63;
  int wm = w >> 2, wn = w & 3;          // 2M x 4N waves, wave owns 128x64
  int l15 = lane & 15, lhi = lane >> 4;
  int wso = w * 1024;                   // per-wave stage offset within region
  int abase0 = wm * 16384;              // A quad 0 (rows wm*128 + 0..63)
  int abase1 = wm * 16384 + 8192;       // A quad 1 (rows wm*128 + 64..127)

  uint32_t alane[2];
  #pragma unroll
  for (int k2 = 0; k2 < 2; k2++)
    alane[k2] = (uint32_t)(l15 * 128 + (((k2 * 4 + lhi) ^ (l15 & 7)) << 4));

  f32x4 acc[8][4];
  #pragma unroll
  for (int mi = 0; mi < 8; mi++)
    #pragma unroll
    for (int ni = 0; ni < 4; ni++) acc[mi][ni] = (f32x4){0.f, 0.f, 0.f, 0.f};
  bf16x8 aq[4][2], bq[4][2];

  // ---- prologue: tile0 fully + tile1's B halves (6 half-tiles) ----
  stage_half(Ab, a_src[0], 0u, lds + 0     + wso);
  stage_half(Ab, a_src[1], 0u, lds + 16384 + wso);
  stage_half(Bb, b_src[0], 0u, lds + 32768 + wso);
  stage_half(Bb, b_src[1], 0u, lds + 49152 + wso);
  if (NTk > 1){
    stage_half(Bb, b_src[0], 128u, lds + 65536 + 32768 + wso);
    stage_half(Bb, b_src[1], 128u, lds + 65536 + 49152 + wso);
    WAITV(4);          // tile0's 8 done; tile1's B stays in flight
  } else {
    WAITV(0);
  }
  BARRIER();

  // ---- main loop: 4 phases per K-tile ----
  #pragma unroll 1
  for (int t = 0; t < NTk; ++t){
    const char* lb = lds + (t & 1) * 65536;          // compute buffer
    char* nb = lds + ((t + 1) & 1) * 65536;          // other buffer (A(t+1))
    char* cb = lds + (t & 1) * 65536;                // this buffer (B(t+2))
    uint32_t ko1 = (uint32_t)(t + 1) * 128u;
    uint32_t ko2 = (uint32_t)(t + 2) * 128u;
    // P0: reads (m0 A-quad + B nh0), stage A-h0(t+1)
    read_Aq(aq, lb, abase0, alane);
    read_Bp<0>(bq, lb, wn, alane);
    if (t + 1 < NTk) stage_half(Ab, a_src[0], ko1, nb + wso);
    BARRIER(); WAITL(0);
    __builtin_amdgcn_s_setprio(1);
    mfma_half<0, 0>(acc, aq, bq);
    __builtin_amdgcn_s_setprio(0);
    BARRIER();
    // P1: reads B nh1, stage A-h1(t+1)
    read_Bp<1>(bq, lb, wn, alane);
    if (t + 1 < NTk) stage_half(Ab, a_src[1], ko1, nb + 16384 + wso);
    BARRIER(); WAITL(0);
    __builtin_amdgcn_s_setprio(1);
    mfma_half<0, 1>(acc, aq, bq);
    __builtin_amdgcn_s_setprio(0);
    BARRIER();
    // P2: reads m1 A-quad, stage B-h0(t+2) (B regions of cb free after P1 bar)
    read_Aq(aq, lb, abase1, alane);
    if (t + 2 < NTk) stage_half(Bb, b_src[0], ko2, cb + 32768 + wso);
    BARRIER(); WAITL(0);
    __builtin_amdgcn_s_setprio(1);
    mfma_half<1, 1>(acc, aq, bq);
    __builtin_amdgcn_s_setprio(0);
    BARRIER();
    // P3: no reads; stage B-h1(t+2); counted vmcnt (drains exactly tile t+1)
    if (t + 2 < NTk) stage_half(Bb, b_src[1], ko2, cb + 49152 + wso);
    __builtin_amdgcn_s_setprio(1);
    mfma_half<1, 0>(acc, aq, bq);
    __builtin_amdgcn_s_setprio(0);
    if (t + 2 < NTk)      { WAITV(4); }
    else if (t + 1 < NTk) { WAITV(0); }
    BARRIER();
  }

  // ---- epilogue: C/D map col = lane&15, row = (lane>>4)*4 + reg ----
  float bv[4]; int nn[4];
  #pragma unroll
  for (int ni = 0; ni < 4; ni++){
    nn[ni] = n0 + wn * 64 + ni * 16 + l15;
    bv[ni] = (MODE == 0 || ksI == 0) ? bias[e * Nd + nn[ni]] : 0.f;
  }
  ushort* OutP = Outp + (size_t)ksI * (size_t)plane_elems;
  #pragma unroll
  for (int mi = 0; mi < 8; mi++){
    #pragma unroll
    for (int r = 0; r < 4; r++){
      int rl = r0l + wm * 128 + mi * 16 + lhi * 4 + r;
      size_t rowbase = (MODE == 0) ? (size_t)rl * Nd
                                   : (size_t)(chunk_base + rl) * Nd;
      #pragma unroll
      for (int ni = 0; ni < 4; ni++){
        float v = acc[mi][ni][r] + bv[ni];
        OutP[rowbase + nn[ni]] = f2bf(v);
      }
    }
  }
}

// ---------------- LayerNorm + tanh-GELU, one block per row, coalesced ----------------
__global__ __launch_bounds__(256) void k_lngelu(
    ushort* __restrict__ h, const int* __restrict__ off,
    const float* __restrict__ lng, const float* __restrict__ lnb, int chunk_base)
{
  __shared__ float redS[8];
  int rl = blockIdx.x, tid = threadIdx.x;
  int grow = chunk_base + rl;
  if (grow >= off[8]) return;
  int e = 0;
  #pragma unroll
  for (int i = 1; i < 8; i++) e = (grow >= off[i]) ? i : e;
  ushort* hr = h + (size_t)rl * Hh;
  // chunk c = i*256+tid, elements [4c, 4c+4): all wave accesses contiguous
  float xv[16];
  #pragma unroll
  for (int i = 0; i < 4; i++){
    int c = i * 256 + tid;
    ushort4 v = *(const ushort4*)(hr + c * 4);
    xv[i * 4 + 0] = bf2f(v.x); xv[i * 4 + 1] = bf2f(v.y);
    xv[i * 4 + 2] = bf2f(v.z); xv[i * 4 + 3] = bf2f(v.w);
  }
  float s0 = 0.f, s1 = 0.f;
  #pragma unroll
  for (int i = 0; i < 16; i++){ s0 += xv[i]; s1 += xv[i] * xv[i]; }
  #pragma unroll
  for (int m = 1; m < 64; m <<= 1){ s0 += __shfl_xor(s0, m, 64); s1 += __shfl_xor(s1, m, 64); }
  int w = tid >> 6;
  if ((tid & 63) == 0){ redS[w * 2] = s0; redS[w * 2 + 1] = s1; }
  __syncthreads();
  s0 = redS[0] + redS[2] + redS[4] + redS[6];
  s1 = redS[1] + redS[3] + redS[5] + redS[7];
  float mu = s0 * (1.f / 4096.f);
  float var = s1 * (1.f / 4096.f) - mu * mu;
  float rs = rsqrtf(var + 1e-5f);
  const float4* gp = (const float4*)(lng + (size_t)e * Hh);
  const float4* bp = (const float4*)(lnb + (size_t)e * Hh);
  #pragma unroll
  for (int i = 0; i < 4; i++){
    int c = i * 256 + tid;
    float4 g = gp[c], b = bp[c];
    float v0 = (xv[i * 4 + 0] - mu) * rs * g.x + b.x;
    float v1 = (xv[i * 4 + 1] - mu) * rs * g.y + b.y;
    float v2 = (xv[i * 4 + 2] - mu) * rs * g.z + b.z;
    float v3 = (xv[i * 4 + 3] - mu) * rs * g.w + b.w;
    ushort4 o;
    o.x = f2bf(gelu_t(v0)); o.y = f2bf(gelu_t(v1));
    o.z = f2bf(gelu_t(v2)); o.w = f2bf(gelu_t(v3));
    *(ushort4*)(hr + c * 4) = o;
  }
}

// -------- combine: out[t] = p0*(y0[p0]+y1[p0]) + p1*(y0[p1]+y1[p1]) --------
__global__ __launch_bounds__(128) void k_combine(
    const ushort* __restrict__ y, int plane, const int2* __restrict__ pidx,
    const float2* __restrict__ topp, float* __restrict__ outp)
{
  int t = blockIdx.x;
  int c4 = threadIdx.x << 2;
  int2 pi = pidx[t]; float2 pp = topp[t];
  ushort4 a0 = *(const ushort4*)(y + (size_t)pi.x * Cc + c4);
  ushort4 a1 = *(const ushort4*)(y + (size_t)plane + (size_t)pi.x * Cc + c4);
  ushort4 b0 = *(const ushort4*)(y + (size_t)pi.y * Cc + c4);
  ushort4 b1 = *(const ushort4*)(y + (size_t)plane + (size_t)pi.y * Cc + c4);
  float4 o;
  o.x = pp.x * (bf2f(a0.x) + bf2f(a1.x)) + pp.y * (bf2f(b0.x) + bf2f(b1.x));
  o.y = pp.x * (bf2f(a0.y) + bf2f(a1.y)) + pp.y * (bf2f(b0.y) + bf2f(b1.y));
  o.z = pp.x * (bf2f(a0.z) + bf2f(a1.z)) + pp.y * (bf2f(b0.z) + bf2f(b1.z));
  o.w = pp.x * (bf2f(a0.w) + bf2f(a1.w)) + pp.y * (bf2f(b0.w) + bf2f(b1.w));
  *(float4*)(outp + (size_t)t * Cc + c4) = o;
}

// ---------------- host launch ----------------
extern "C" void kernel_launch(void* const* d_in, const int* in_sizes, int n_in,
                              void* d_out, int out_size, void* d_ws, size_t ws_size,
                              hipStream_t stream)
{
  const float* x   = (const float*)d_in[0];
  const float* gw  = (const float*)d_in[1];
  const float* gb  = (const float*)d_in[2];
  const float* w1  = (const float*)d_in[3];
  const float* b1  = (const float*)d_in[4];
  const float* lng = (const float*)d_in[5];
  const float* lnb = (const float*)d_in[6];
  const float* w2  = (const float*)d_in[7];
  const float* b2  = (const float*)d_in[8];
  float* outp   = (float*)d_out;
  float* logits = outp + (size_t)Bt * Cc;

  constexpr int YPLANE = PCAP * Cc;   // elements per split-K plane

  char* p = (char*)d_ws;
  auto alloc = [&](size_t bytes) -> char* {
    char* q = p; p += (bytes + 255) & ~(size_t)255; return q;
  };
  int*    ctrl  = (int*)alloc(256);            // fill[8] @ +8 | off[9] @ +16
  int* fill = ctrl + 8; int* off = ctrl + 16;
  int2*   topi  = (int2*)alloc((size_t)Bt * 8);
  float2* topp  = (float2*)alloc((size_t)Bt * 8);
  int2*   pidx  = (int2*)alloc((size_t)Bt * 8);
  int*    ptok  = (int*)alloc((size_t)PCAP * 4);
  ushort* ybuf  = (ushort*)alloc((size_t)YPLANE * 2 * 2);   // 2 planes bf16
  ushort* xb    = (ushort*)alloc((size_t)Bt * Dd * 2);
  ushort* w1t   = (ushort*)alloc((size_t)Ee * Hh * Dd * 2);
  ushort* w2t   = (ushort*)alloc((size_t)Ee * Cc * Hh * 2);
  size_t used  = (size_t)(p - (char*)d_ws);
  size_t avail = ws_size > used ? ws_size - used : 0;
  long long chr = (long long)(avail / ((size_t)Hh * 2));
  chr &= ~255LL;
  int CH = (int)(chr < 256 ? 256 : (chr > PCAP ? (long long)PCAP : chr));
  ushort* hbuf = (ushort*)p;   // CH x Hh bf16

  hipMemsetAsync(ctrl, 0, 256, stream);
  hipMemsetAsync(ptok, 0, (size_t)PCAP * 4, stream);

  k_routercvt<<<Bt / 4, 256, 0, stream>>>(x, gw, gb, logits, topi, topp, xb);
  k_offsets<<<1, 256, 0, stream>>>(topi, off);
  k_scatter<<<Bt / 256, 256, 0, stream>>>(topi, off, fill, ptok, pidx);
  k_transpose_bf16<<<dim3(Hh / 64, Dd / 64, Ee), 256, 0, stream>>>(w1, w1t, Dd, Hh);
  k_transpose_bf16<<<dim3(Cc / 64, Hh / 64, Ee), 256, 0, stream>>>(w2, w2t, Hh, Cc);

  for (int base = 0; base < PCAP; base += CH){
    int rows = (PCAP - base < CH) ? (PCAP - base) : CH;
    int nb1 = (rows / 256) * (Hh / 256);
    k_gemm8<0, Dd, Hh, 1><<<nb1, 512, 0, stream>>>(xb, w1t, b1, off, ptok, hbuf, base, 0);
    k_lngelu<<<rows, 256, 0, stream>>>(hbuf, off, lng, lnb, base);
    int nb2 = (rows / 256) * (Cc / 256) * 2;
    k_gemm8<1, Hh, Cc, 2><<<nb2, 512, 0, stream>>>(hbuf, w2t, b2, off, ptok, ybuf, base, YPLANE);
  }
  k_combine<<<Bt, 128, 0, stream>>>(ybuf, YPLANE, pidx, topp, outp);
}